// Round 5
// baseline (532.321 us; speedup 1.0000x reference)
//
#include <hip/hip_runtime.h>
#include <hip/hip_bf16.h>
#include <math.h>

// ===========================================================================
// f64-accumulate / f32-storage-grid pipeline (R2/R3 numerics, proven).
// R4: conv split into two high-occupancy kernels (bit-identical op order);
// GEMM retiled 128x64 with 8x4 microtile + split-K 8 for VALU issue density.
// ===========================================================================

// ---------------------------------------------------------------------------
// conv1: conv(1->8,3x3,SAME) + bias + relu + maxpool2 -> feat1 [1024,8,32,32]
// f64 accumulate over f32 inputs, f32 storage grid. Each thread: 4 pooled
// outputs in a row from a shared 4x10 input region.
// ---------------------------------------------------------------------------
__global__ __launch_bounds__(256) void conv1_kernel(
    const float* __restrict__ x, const float* __restrict__ cw1,
    const float* __restrict__ cb1, float* __restrict__ feat1) {
  __shared__ float sX[66 * 66];
  __shared__ float sW1[72];
  __shared__ float sB1[8];

  const int b = blockIdx.x;
  const int t = threadIdx.x;

  for (int i = t; i < 66 * 66; i += 256) sX[i] = 0.0f;
  if (t < 72) sW1[t] = cw1[t];
  if (t < 8)  sB1[t] = cb1[t];
  __syncthreads();

  const float* xb = x + (size_t)b * 4096;
  for (int i = t; i < 4096; i += 256)
    sX[((i >> 6) + 1) * 66 + (i & 63) + 1] = xb[i];
  __syncthreads();

  // 2048 tasks: ch(8) x py(32) x xg(8); each = 4 pooled outputs along x
  for (int task = t; task < 2048; task += 256) {
    const int ch = task >> 8;
    const int rem = task & 255;
    const int py = rem >> 3;
    const int px0 = (rem & 7) * 4;

    double w9[9];
#pragma unroll
    for (int k = 0; k < 9; ++k) w9[k] = (double)sW1[ch * 9 + k];

    float reg[4][10];
#pragma unroll
    for (int r = 0; r < 4; ++r)
#pragma unroll
      for (int c = 0; c < 5; ++c) {
        const float2 v =
            *(const float2*)&sX[(2 * py + r) * 66 + 2 * px0 + 2 * c];
        reg[r][2 * c] = v.x;
        reg[r][2 * c + 1] = v.y;
      }

    float out4[4];
#pragma unroll
    for (int px = 0; px < 4; ++px) {
      double best = -1e300;
#pragma unroll
      for (int dy = 0; dy < 2; ++dy) {
#pragma unroll
        for (int dx = 0; dx < 2; ++dx) {
          double s = 0.0;
#pragma unroll
          for (int ky = 0; ky < 3; ++ky)
#pragma unroll
            for (int kx = 0; kx < 3; ++kx)
              s = fma((double)reg[dy + ky][2 * px + dx + kx], w9[ky * 3 + kx],
                      s);
          best = fmax(best, s);
        }
      }
      out4[px] = (float)fmax(best + (double)sB1[ch], 0.0);
    }
    *(float4*)&feat1[(size_t)b * 8192 + ch * 1024 + py * 32 + px0] =
        make_float4(out4[0], out4[1], out4[2], out4[3]);
  }
}

// ---------------------------------------------------------------------------
// conv2: conv(8->16,3x3,SAME) + bias + relu + maxpool2 -> flat [1024,4096]
// Stages feat1 (f32 grid) into padded LDS; oc-pair loop bounds VGPRs.
// Per-element f64 accumulation order identical to the R2/R3 fused kernel.
// ---------------------------------------------------------------------------
__global__ __launch_bounds__(256) void conv2_kernel(
    const float* __restrict__ feat1, const float* __restrict__ cw2,
    const float* __restrict__ cb2, float* __restrict__ flat) {
  __shared__ float sF[8 * 34 * 34];
  __shared__ float sW2[1152];
  __shared__ float sB2[16];

  const int b = blockIdx.x;
  const int t = threadIdx.x;

  for (int i = t; i < 8 * 34 * 34; i += 256) sF[i] = 0.0f;
  for (int i = t; i < 1152; i += 256) sW2[i] = cw2[i];
  if (t < 16) sB2[t] = cb2[t];
  __syncthreads();

  const float* fb = feat1 + (size_t)b * 8192;
  for (int i = t; i < 8192; i += 256) {
    const int ch = i >> 10, pos = i & 1023;
    sF[ch * 1156 + ((pos >> 5) + 1) * 34 + (pos & 31) + 1] = fb[i];
  }
  __syncthreads();

  const int py = t >> 4, px = t & 15;
  float* ob = flat + (size_t)b * 4096 + py * 16 + px;

  for (int pair = 0; pair < 8; ++pair) {
    double acc[2][4];
#pragma unroll
    for (int o = 0; o < 2; ++o)
#pragma unroll
      for (int q = 0; q < 4; ++q) acc[o][q] = 0.0;

#pragma unroll
    for (int ic = 0; ic < 8; ++ic) {
      double r[4][4];
#pragma unroll
      for (int iy = 0; iy < 4; ++iy) {
        const float2 v0 =
            *(const float2*)&sF[ic * 1156 + (2 * py + iy) * 34 + 2 * px];
        const float2 v1 =
            *(const float2*)&sF[ic * 1156 + (2 * py + iy) * 34 + 2 * px + 2];
        r[iy][0] = (double)v0.x; r[iy][1] = (double)v0.y;
        r[iy][2] = (double)v1.x; r[iy][3] = (double)v1.y;
      }
#pragma unroll
      for (int o = 0; o < 2; ++o) {
        const int oc = 2 * pair + o;
        double w9[9];
#pragma unroll
        for (int k = 0; k < 9; ++k) w9[k] = (double)sW2[oc * 72 + ic * 9 + k];
#pragma unroll
        for (int dy = 0; dy < 2; ++dy)
#pragma unroll
          for (int dx = 0; dx < 2; ++dx) {
            double s = acc[o][dy * 2 + dx];
#pragma unroll
            for (int ky = 0; ky < 3; ++ky)
#pragma unroll
              for (int kx = 0; kx < 3; ++kx)
                s = fma(r[dy + ky][dx + kx], w9[ky * 3 + kx], s);
            acc[o][dy * 2 + dx] = s;
          }
      }
    }
#pragma unroll
    for (int o = 0; o < 2; ++o) {
      const int oc = 2 * pair + o;
      const double best =
          fmax(fmax(acc[o][0], acc[o][1]), fmax(acc[o][2], acc[o][3]));
      ob[oc * 256] = (float)fmax(best + (double)sB2[oc], 0.0);
    }
  }
}

// ---------------------------------------------------------------------------
// Fallback fused conv (R2/R3 kernel) for small-ws path.
// ---------------------------------------------------------------------------
__global__ __launch_bounds__(256) void conv_fused(
    const float* __restrict__ x,
    const float* __restrict__ cw1, const float* __restrict__ cb1,
    const float* __restrict__ cw2, const float* __restrict__ cb2,
    float* __restrict__ flat) {
  __shared__ float sX[66 * 66];
  __shared__ float sF[8 * 34 * 34];
  __shared__ float sW1[72];
  __shared__ float sW2[1152];
  __shared__ float sB1[8];
  __shared__ float sB2[16];

  const int b = blockIdx.x;
  const int t = threadIdx.x;

  for (int i = t; i < 66 * 66; i += 256) sX[i] = 0.0f;
  for (int i = t; i < 8 * 34 * 34; i += 256) sF[i] = 0.0f;
  if (t < 72) sW1[t] = cw1[t];
  for (int i = t; i < 1152; i += 256) sW2[i] = cw2[i];
  if (t < 8)  sB1[t] = cb1[t];
  if (t < 16) sB2[t] = cb2[t];
  __syncthreads();

  const float* xb = x + (size_t)b * 4096;
  for (int i = t; i < 4096; i += 256)
    sX[((i >> 6) + 1) * 66 + (i & 63) + 1] = xb[i];
  __syncthreads();

  for (int p = t; p < 8192; p += 256) {
    const int ch = p >> 10, pos = p & 1023;
    const int py1 = pos >> 5, px1 = pos & 31;
    double best = -1e300;
#pragma unroll
    for (int dy = 0; dy < 2; ++dy)
#pragma unroll
      for (int dx = 0; dx < 2; ++dx) {
        const int y = 2 * py1 + dy, xx = 2 * px1 + dx;
        double s = 0.0;
#pragma unroll
        for (int ky = 0; ky < 3; ++ky)
#pragma unroll
          for (int kx = 0; kx < 3; ++kx)
            s = fma((double)sX[(y + ky) * 66 + xx + kx],
                    (double)sW1[ch * 9 + ky * 3 + kx], s);
        best = fmax(best, s);
      }
    sF[ch * 1156 + (py1 + 1) * 34 + px1 + 1] =
        (float)fmax(best + (double)sB1[ch], 0.0);
  }
  __syncthreads();

  const int py = t >> 4, px = t & 15;
  for (int oh = 0; oh < 2; ++oh) {
    double acc[8][4];
#pragma unroll
    for (int o = 0; o < 8; ++o)
#pragma unroll
      for (int q = 0; q < 4; ++q) acc[o][q] = 0.0;
#pragma unroll
    for (int ic = 0; ic < 8; ++ic) {
      double r[4][4];
#pragma unroll
      for (int iy = 0; iy < 4; ++iy)
#pragma unroll
        for (int ix = 0; ix < 4; ++ix)
          r[iy][ix] = (double)sF[ic * 1156 + (2 * py + iy) * 34 + 2 * px + ix];
#pragma unroll
      for (int o = 0; o < 8; ++o) {
        const float* w = &sW2[(oh * 8 + o) * 72 + ic * 9];
        double w9[9];
#pragma unroll
        for (int k = 0; k < 9; ++k) w9[k] = (double)w[k];
#pragma unroll
        for (int dy = 0; dy < 2; ++dy)
#pragma unroll
          for (int dx = 0; dx < 2; ++dx) {
            double s = acc[o][dy * 2 + dx];
#pragma unroll
            for (int ky = 0; ky < 3; ++ky)
#pragma unroll
              for (int kx = 0; kx < 3; ++kx)
                s = fma(r[dy + ky][dx + kx], w9[ky * 3 + kx], s);
            acc[o][dy * 2 + dx] = s;
          }
      }
    }
    float* ob = flat + (size_t)b * 4096 + py * 16 + px;
#pragma unroll
    for (int o = 0; o < 8; ++o) {
      const int oc = oh * 8 + o;
      double best =
          fmax(fmax(acc[o][0], acc[o][1]), fmax(acc[o][2], acc[o][3]));
      ob[oc * 256] = (float)fmax(best + (double)sB2[oc], 0.0);
    }
  }
}

// ---------------------------------------------------------------------------
// Split-K NT GEMM v2: 128x64 tile, BK=16, 8x4 microtile, f64 accumulate.
// P[s][m*N+n] = sum_{k in chunk s} A[m,k]*B[n,k]  (k ascending)
// M % 128 == 0, N % 64 == 0, Kc % 16 == 0.
// ---------------------------------------------------------------------------
__global__ __launch_bounds__(256) void gemm_nt_f64_v2(
    const float* __restrict__ A, const float* __restrict__ B,
    double* __restrict__ P, int M, int N, int K, int Kc) {
  __shared__ double As[16][130];  // 16.6 KB
  __shared__ double Bs[16][66];   //  8.4 KB

  const int t = threadIdx.x;
  const int n0 = blockIdx.x * 64;
  const int m0 = blockIdx.y * 128;
  const int s  = blockIdx.z;
  const int kb = s * Kc;
  const int rS = t >> 2;            // 0..63 staging row
  const int cS = (t & 3) * 4;       // staging k offset 0,4,8,12
  const int ty = t >> 4;            // 0..15
  const int tx = t & 15;            // 0..15

  double acc[8][4];
#pragma unroll
  for (int i = 0; i < 8; ++i)
#pragma unroll
    for (int j = 0; j < 4; ++j) acc[i][j] = 0.0;

  for (int k0 = kb; k0 < kb + Kc; k0 += 16) {
    const float4 aLo = *(const float4*)&A[(size_t)(m0 + rS) * K + k0 + cS];
    const float4 aHi = *(const float4*)&A[(size_t)(m0 + 64 + rS) * K + k0 + cS];
    const float4 bV  = *(const float4*)&B[(size_t)(n0 + rS) * K + k0 + cS];
    __syncthreads();
    As[cS + 0][rS] = (double)aLo.x; As[cS + 1][rS] = (double)aLo.y;
    As[cS + 2][rS] = (double)aLo.z; As[cS + 3][rS] = (double)aLo.w;
    As[cS + 0][64 + rS] = (double)aHi.x; As[cS + 1][64 + rS] = (double)aHi.y;
    As[cS + 2][64 + rS] = (double)aHi.z; As[cS + 3][64 + rS] = (double)aHi.w;
    Bs[cS + 0][rS] = (double)bV.x; Bs[cS + 1][rS] = (double)bV.y;
    Bs[cS + 2][rS] = (double)bV.z; Bs[cS + 3][rS] = (double)bV.w;
    __syncthreads();
#pragma unroll
    for (int k = 0; k < 16; ++k) {
      const double2 a0 = *(const double2*)&As[k][2 * ty];
      const double2 a1 = *(const double2*)&As[k][32 + 2 * ty];
      const double2 a2 = *(const double2*)&As[k][64 + 2 * ty];
      const double2 a3 = *(const double2*)&As[k][96 + 2 * ty];
      const double2 b0 = *(const double2*)&Bs[k][2 * tx];
      const double2 b1 = *(const double2*)&Bs[k][32 + 2 * tx];
      const double ar[8] = {a0.x, a0.y, a1.x, a1.y, a2.x, a2.y, a3.x, a3.y};
      const double br[4] = {b0.x, b0.y, b1.x, b1.y};
#pragma unroll
      for (int i = 0; i < 8; ++i)
#pragma unroll
        for (int j = 0; j < 4; ++j)
          acc[i][j] = fma(ar[i], br[j], acc[i][j]);
    }
  }

  double* Pp = P + (size_t)s * M * N;
  const int c0 = n0 + 2 * tx, c1 = n0 + 32 + 2 * tx;
#pragma unroll
  for (int i = 0; i < 8; ++i) {
    const int row = m0 + (i >> 1) * 32 + 2 * ty + (i & 1);
    *(double2*)&Pp[(size_t)row * N + c0] = make_double2(acc[i][0], acc[i][1]);
    *(double2*)&Pp[(size_t)row * N + c1] = make_double2(acc[i][2], acc[i][3]);
  }
}

// ---------------------------------------------------------------------------
// Reduce S f64 partials (ascending) + tanh epilogue on the f32 grid.
// ---------------------------------------------------------------------------
__global__ __launch_bounds__(256) void reduce_tanh(
    const double* __restrict__ P, int S, const float* __restrict__ bias,
    float* __restrict__ C, int N, int total) {
  const int idx = blockIdx.x * 256 + threadIdx.x;
  if (idx >= total) return;
  double sum = 0.0;
  for (int s = 0; s < S; ++s) sum += P[(size_t)s * total + idx];
  const float zg = (float)sum;
  const float z = zg + bias[idx % N];
  C[idx] = (float)tanh((double)z);
}

// ---------------------------------------------------------------------------
// Reduce partials + adjacency epilogue on the f32 grid.
// ---------------------------------------------------------------------------
__global__ __launch_bounds__(256) void reduce_adj(
    const double* __restrict__ P, int S, float* __restrict__ adj, int N) {
  const int idx = blockIdx.x * 256 + threadIdx.x;
  const int total = N * N;
  if (idx >= total) return;
  double sum = 0.0;
  for (int s = 0; s < S; ++s) sum += P[(size_t)s * total + idx];
  const float g = (float)sum;
  const float fid = g * g;
  float v = (fid >= 0.8f) ? 1.0f : ((fid >= 0.6f) ? 0.5f : 0.0f);
  if (idx / N == idx % N) v = 0.0f;
  adj[idx] = v;
}

// ---------------------------------------------------------------------------
__global__ __launch_bounds__(256) void rownorm(
    const float* __restrict__ last, float* __restrict__ nrm) {
  const int b = blockIdx.x;
  const int t = threadIdx.x;
  const float v = last[(size_t)b * 256 + t];
  const float sq = v * v;
  double s = (double)sq;
#pragma unroll
  for (int o = 32; o > 0; o >>= 1) s += __shfl_down(s, o);
  __shared__ double red[4];
  if ((t & 63) == 0) red[t >> 6] = s;
  __syncthreads();
  const double total = red[0] + red[1] + red[2] + red[3];
  const float s32 = (float)total;
  const float den = sqrtf(s32) + 1e-12f;
  nrm[(size_t)b * 256 + t] = v / den;
}

// ---------------------------------------------------------------------------
__global__ __launch_bounds__(256) void bn_stats(
    const float* __restrict__ last, const float* __restrict__ gamma,
    const float* __restrict__ beta, float* __restrict__ out) {
  const int j = blockIdx.x;
  const int t = threadIdx.x;
  double v[4];
  double s = 0.0;
#pragma unroll
  for (int i = 0; i < 4; ++i) {
    v[i] = (double)last[(size_t)(i * 256 + t) * 256 + j];
    s += v[i];
  }
#pragma unroll
  for (int o = 32; o > 0; o >>= 1) s += __shfl_down(s, o);
  __shared__ double red[4];
  if ((t & 63) == 0) red[t >> 6] = s;
  __syncthreads();
  const double mean = (red[0] + red[1] + red[2] + red[3]) * (1.0 / 1024.0);
  double q = 0.0;
#pragma unroll
  for (int i = 0; i < 4; ++i) {
    const double d = v[i] - mean;
    q += d * d;
  }
#pragma unroll
  for (int o = 32; o > 0; o >>= 1) q += __shfl_down(q, o);
  __syncthreads();
  if ((t & 63) == 0) red[t >> 6] = q;
  __syncthreads();
  const double var = (red[0] + red[1] + red[2] + red[3]) * (1.0 / 1024.0);
  const double g = (double)gamma[j] / sqrt(var + 1e-5);
  const double be = (double)beta[j];
#pragma unroll
  for (int i = 0; i < 4; ++i)
    out[(size_t)(i * 256 + t) * 256 + j] = (float)((v[i] - mean) * g + be);
}

// ---------------------------------------------------------------------------
extern "C" void kernel_launch(void* const* d_in, const int* in_sizes, int n_in,
                              void* d_out, int out_size, void* d_ws,
                              size_t ws_size, hipStream_t stream) {
  const float* x     = (const float*)d_in[0];
  const float* cw1   = (const float*)d_in[1];
  const float* cb1   = (const float*)d_in[2];
  const float* cw2   = (const float*)d_in[3];
  const float* cb2   = (const float*)d_in[4];
  const float* w1    = (const float*)d_in[5];   // [1024,4096]
  const float* b1    = (const float*)d_in[6];
  const float* w2    = (const float*)d_in[7];   // [256,1024]
  const float* b2    = (const float*)d_in[8];
  const float* gamma = (const float*)d_in[9];
  const float* beta  = (const float*)d_in[10];

  float* outp = (float*)d_out;            // [1024,256]
  float* adj  = outp + 1024 * 256;        // [1024,1024]

  float* ws   = (float*)d_ws;
  float* flat = ws;                       // [1024,4096] @0        16.78 MB
  float* h1   = ws + 4194304;             // [1024,1024]            4.19 MB
  float* last = ws + 5242880;             // [1024,256]             1.05 MB
  float* nrm  = ws + 5505024;             // [1024,256]             1.05 MB
  double* part = (double*)(ws + 5767168); // partial region @23.07 MB
  float* feat1 = (float*)part;            // [1024,8,32,32] 33.55 MB,
                                          // dead before first GEMM

  // ws gates (deterministic): S=8 partials 67.1MB -> 90.2MB total;
  // S=4 -> 56.6MB; else S=2 + fused conv (feat1 wouldn't fit).
  const size_t baseB = 5767168ull * 4ull;
  int S1;
  if (ws_size >= baseB + 8ull * 1024 * 1024 * 8) S1 = 8;
  else if (ws_size >= baseB + 4ull * 1024 * 1024 * 8) S1 = 4;
  else S1 = 2;
  const int S2 = (S1 >= 4) ? 16 : 4;      // gemm2 split (33.5MB / 8.4MB)
  const bool split_conv = (S1 >= 4);

  if (split_conv) {
    conv1_kernel<<<1024, 256, 0, stream>>>(x, cw1, cb1, feat1);
    conv2_kernel<<<1024, 256, 0, stream>>>(feat1, cw2, cb2, flat);
  } else {
    conv_fused<<<1024, 256, 0, stream>>>(x, cw1, cb1, cw2, cb2, flat);
  }

  // h1 = tanh(flat @ w1^T + b1)   [1024,1024], K=4096
  gemm_nt_f64_v2<<<dim3(16, 8, S1), 256, 0, stream>>>(
      flat, w1, part, 1024, 1024, 4096, 4096 / S1);
  reduce_tanh<<<4096, 256, 0, stream>>>(part, S1, b1, h1, 1024, 1024 * 1024);

  // last = tanh(h1 @ w2^T + b2)   [1024,256], K=1024
  gemm_nt_f64_v2<<<dim3(4, 8, S2), 256, 0, stream>>>(
      h1, w2, part, 1024, 256, 1024, 1024 / S2);
  reduce_tanh<<<1024, 256, 0, stream>>>(part, S2, b2, last, 256, 1024 * 256);

  rownorm<<<1024, 256, 0, stream>>>(last, nrm);

  // adj = thr((nrm @ nrm^T)^2), zero diag; K=256, split 2
  gemm_nt_f64_v2<<<dim3(16, 8, 2), 256, 0, stream>>>(
      nrm, nrm, part, 1024, 1024, 256, 128);
  reduce_adj<<<4096, 256, 0, stream>>>(part, 2, adj, 1024);

  bn_stats<<<256, 256, 0, stream>>>(last, gamma, beta, outp);
}

// Round 6
// 428.775 us; speedup vs baseline: 1.2415x; 1.2415x over previous
//
#include <hip/hip_runtime.h>
#include <hip/hip_bf16.h>
#include <math.h>

// ===========================================================================
// f64-accumulate / f32-storage-grid pipeline (R2/R3 numerics, proven).
// R5: conv2 reverted to the R2-proven register structure (R4's pair-loop
// variant spilled: VGPR=256, 473 MB scratch traffic = the whole 233 us).
// GEMM: 128x128 tile, 8x8 microtile, software-pipelined global prefetch.
// ===========================================================================

// ---------------------------------------------------------------------------
// conv1: conv(1->8,3x3,SAME) + bias + relu + maxpool2 -> feat1 [1024,8,32,32]
// ---------------------------------------------------------------------------
__global__ __launch_bounds__(256) void conv1_kernel(
    const float* __restrict__ x, const float* __restrict__ cw1,
    const float* __restrict__ cb1, float* __restrict__ feat1) {
  __shared__ float sX[66 * 66];
  __shared__ float sW1[72];
  __shared__ float sB1[8];

  const int b = blockIdx.x;
  const int t = threadIdx.x;

  for (int i = t; i < 66 * 66; i += 256) sX[i] = 0.0f;
  if (t < 72) sW1[t] = cw1[t];
  if (t < 8)  sB1[t] = cb1[t];
  __syncthreads();

  const float* xb = x + (size_t)b * 4096;
  for (int i = t; i < 4096; i += 256)
    sX[((i >> 6) + 1) * 66 + (i & 63) + 1] = xb[i];
  __syncthreads();

  for (int task = t; task < 2048; task += 256) {
    const int ch = task >> 8;
    const int rem = task & 255;
    const int py = rem >> 3;
    const int px0 = (rem & 7) * 4;

    double w9[9];
#pragma unroll
    for (int k = 0; k < 9; ++k) w9[k] = (double)sW1[ch * 9 + k];

    float reg[4][10];
#pragma unroll
    for (int r = 0; r < 4; ++r)
#pragma unroll
      for (int c = 0; c < 5; ++c) {
        const float2 v =
            *(const float2*)&sX[(2 * py + r) * 66 + 2 * px0 + 2 * c];
        reg[r][2 * c] = v.x;
        reg[r][2 * c + 1] = v.y;
      }

    float out4[4];
#pragma unroll
    for (int px = 0; px < 4; ++px) {
      double best = -1e300;
#pragma unroll
      for (int dy = 0; dy < 2; ++dy) {
#pragma unroll
        for (int dx = 0; dx < 2; ++dx) {
          double s = 0.0;
#pragma unroll
          for (int ky = 0; ky < 3; ++ky)
#pragma unroll
            for (int kx = 0; kx < 3; ++kx)
              s = fma((double)reg[dy + ky][2 * px + dx + kx], w9[ky * 3 + kx],
                      s);
          best = fmax(best, s);
        }
      }
      out4[px] = (float)fmax(best + (double)sB1[ch], 0.0);
    }
    *(float4*)&feat1[(size_t)b * 8192 + ch * 1024 + py * 32 + px0] =
        make_float4(out4[0], out4[1], out4[2], out4[3]);
  }
}

// ---------------------------------------------------------------------------
// conv2: conv(8->16,3x3,SAME) + bias + relu + maxpool2 -> flat [1024,4096]
// EXACT R2/R3-proven compute structure (oh halves, acc[8][4]); the only
// change: receptive patch r kept as f32, converted at each fma (exact, so
// f64 op order is bit-identical). R4's pair-loop variant hit VGPR=256+spill.
// ---------------------------------------------------------------------------
__global__ __launch_bounds__(256) void conv2_kernel(
    const float* __restrict__ feat1, const float* __restrict__ cw2,
    const float* __restrict__ cb2, float* __restrict__ flat) {
  __shared__ float sF[8 * 34 * 34];
  __shared__ float sW2[1152];
  __shared__ float sB2[16];

  const int b = blockIdx.x;
  const int t = threadIdx.x;

  for (int i = t; i < 8 * 34 * 34; i += 256) sF[i] = 0.0f;
  for (int i = t; i < 1152; i += 256) sW2[i] = cw2[i];
  if (t < 16) sB2[t] = cb2[t];
  __syncthreads();

  const float* fb = feat1 + (size_t)b * 8192;
  for (int i = t; i < 8192; i += 256) {
    const int ch = i >> 10, pos = i & 1023;
    sF[ch * 1156 + ((pos >> 5) + 1) * 34 + (pos & 31) + 1] = fb[i];
  }
  __syncthreads();

  const int py = t >> 4, px = t & 15;
  float* ob = flat + (size_t)b * 4096 + py * 16 + px;

#pragma unroll 1
  for (int oh = 0; oh < 2; ++oh) {
    double acc[8][4];
#pragma unroll
    for (int o = 0; o < 8; ++o)
#pragma unroll
      for (int q = 0; q < 4; ++q) acc[o][q] = 0.0;

#pragma unroll
    for (int ic = 0; ic < 8; ++ic) {
      float r[4][4];
#pragma unroll
      for (int iy = 0; iy < 4; ++iy) {
        const float2 v0 =
            *(const float2*)&sF[ic * 1156 + (2 * py + iy) * 34 + 2 * px];
        const float2 v1 =
            *(const float2*)&sF[ic * 1156 + (2 * py + iy) * 34 + 2 * px + 2];
        r[iy][0] = v0.x; r[iy][1] = v0.y; r[iy][2] = v1.x; r[iy][3] = v1.y;
      }
#pragma unroll
      for (int o = 0; o < 8; ++o) {
        const float* w = &sW2[(oh * 8 + o) * 72 + ic * 9];
        double w9[9];
#pragma unroll
        for (int k = 0; k < 9; ++k) w9[k] = (double)w[k];
#pragma unroll
        for (int dy = 0; dy < 2; ++dy)
#pragma unroll
          for (int dx = 0; dx < 2; ++dx) {
            double s = acc[o][dy * 2 + dx];
#pragma unroll
            for (int ky = 0; ky < 3; ++ky)
#pragma unroll
              for (int kx = 0; kx < 3; ++kx)
                s = fma((double)r[dy + ky][dx + kx], w9[ky * 3 + kx], s);
            acc[o][dy * 2 + dx] = s;
          }
      }
    }
#pragma unroll
    for (int o = 0; o < 8; ++o) {
      const int oc = oh * 8 + o;
      const double best =
          fmax(fmax(acc[o][0], acc[o][1]), fmax(acc[o][2], acc[o][3]));
      ob[oc * 256] = (float)fmax(best + (double)sB2[oc], 0.0);
    }
  }
}

// ---------------------------------------------------------------------------
// Fallback fused conv (R2/R3 kernel) for small-ws path.
// ---------------------------------------------------------------------------
__global__ __launch_bounds__(256) void conv_fused(
    const float* __restrict__ x,
    const float* __restrict__ cw1, const float* __restrict__ cb1,
    const float* __restrict__ cw2, const float* __restrict__ cb2,
    float* __restrict__ flat) {
  __shared__ float sX[66 * 66];
  __shared__ float sF[8 * 34 * 34];
  __shared__ float sW1[72];
  __shared__ float sW2[1152];
  __shared__ float sB1[8];
  __shared__ float sB2[16];

  const int b = blockIdx.x;
  const int t = threadIdx.x;

  for (int i = t; i < 66 * 66; i += 256) sX[i] = 0.0f;
  for (int i = t; i < 8 * 34 * 34; i += 256) sF[i] = 0.0f;
  if (t < 72) sW1[t] = cw1[t];
  for (int i = t; i < 1152; i += 256) sW2[i] = cw2[i];
  if (t < 8)  sB1[t] = cb1[t];
  if (t < 16) sB2[t] = cb2[t];
  __syncthreads();

  const float* xb = x + (size_t)b * 4096;
  for (int i = t; i < 4096; i += 256)
    sX[((i >> 6) + 1) * 66 + (i & 63) + 1] = xb[i];
  __syncthreads();

  for (int p = t; p < 8192; p += 256) {
    const int ch = p >> 10, pos = p & 1023;
    const int py1 = pos >> 5, px1 = pos & 31;
    double best = -1e300;
#pragma unroll
    for (int dy = 0; dy < 2; ++dy)
#pragma unroll
      for (int dx = 0; dx < 2; ++dx) {
        const int y = 2 * py1 + dy, xx = 2 * px1 + dx;
        double s = 0.0;
#pragma unroll
        for (int ky = 0; ky < 3; ++ky)
#pragma unroll
          for (int kx = 0; kx < 3; ++kx)
            s = fma((double)sX[(y + ky) * 66 + xx + kx],
                    (double)sW1[ch * 9 + ky * 3 + kx], s);
        best = fmax(best, s);
      }
    sF[ch * 1156 + (py1 + 1) * 34 + px1 + 1] =
        (float)fmax(best + (double)sB1[ch], 0.0);
  }
  __syncthreads();

  const int py = t >> 4, px = t & 15;
  for (int oh = 0; oh < 2; ++oh) {
    double acc[8][4];
#pragma unroll
    for (int o = 0; o < 8; ++o)
#pragma unroll
      for (int q = 0; q < 4; ++q) acc[o][q] = 0.0;
#pragma unroll
    for (int ic = 0; ic < 8; ++ic) {
      double r[4][4];
#pragma unroll
      for (int iy = 0; iy < 4; ++iy)
#pragma unroll
        for (int ix = 0; ix < 4; ++ix)
          r[iy][ix] = (double)sF[ic * 1156 + (2 * py + iy) * 34 + 2 * px + ix];
#pragma unroll
      for (int o = 0; o < 8; ++o) {
        const float* w = &sW2[(oh * 8 + o) * 72 + ic * 9];
        double w9[9];
#pragma unroll
        for (int k = 0; k < 9; ++k) w9[k] = (double)w[k];
#pragma unroll
        for (int dy = 0; dy < 2; ++dy)
#pragma unroll
          for (int dx = 0; dx < 2; ++dx) {
            double s = acc[o][dy * 2 + dx];
#pragma unroll
            for (int ky = 0; ky < 3; ++ky)
#pragma unroll
              for (int kx = 0; kx < 3; ++kx)
                s = fma(r[dy + ky][dx + kx], w9[ky * 3 + kx], s);
            acc[o][dy * 2 + dx] = s;
          }
      }
    }
    float* ob = flat + (size_t)b * 4096 + py * 16 + px;
#pragma unroll
    for (int o = 0; o < 8; ++o) {
      const int oc = oh * 8 + o;
      double best =
          fmax(fmax(acc[o][0], acc[o][1]), fmax(acc[o][2], acc[o][3]));
      ob[oc * 256] = (float)fmax(best + (double)sB2[oc], 0.0);
    }
  }
}

// ---------------------------------------------------------------------------
// Split-K NT GEMM v3: 128x128 tile, BK=16, 8x8 microtile, f64 accumulate,
// software-pipelined global prefetch. k ascending within each chunk
// (bit-identical partial sums regardless of tiling).
// M % 128 == 0, N % 128 == 0, Kc % 16 == 0.
// ---------------------------------------------------------------------------
__global__ __launch_bounds__(256) void gemm_nt_f64_v3(
    const float* __restrict__ A, const float* __restrict__ B,
    double* __restrict__ P, int M, int N, int K, int Kc) {
  __shared__ double As[16][130];  // 16.6 KB
  __shared__ double Bs[16][130];  // 16.6 KB

  const int t = threadIdx.x;
  const int n0 = blockIdx.x * 128;
  const int m0 = blockIdx.y * 128;
  const int s  = blockIdx.z;
  const int kb = s * Kc;
  const int rS = t >> 2;            // 0..63 staging row
  const int cS = (t & 3) * 4;       // staging k offset 0,4,8,12
  const int ty = t >> 4;            // 0..15
  const int tx = t & 15;            // 0..15

  double acc[8][8];
#pragma unroll
  for (int i = 0; i < 8; ++i)
#pragma unroll
    for (int j = 0; j < 8; ++j) acc[i][j] = 0.0;

  const float* Alo = &A[(size_t)(m0 + rS) * K + cS];
  const float* Ahi = &A[(size_t)(m0 + 64 + rS) * K + cS];
  const float* Blo = &B[(size_t)(n0 + rS) * K + cS];
  const float* Bhi = &B[(size_t)(n0 + 64 + rS) * K + cS];

  float4 a0 = *(const float4*)&Alo[kb];
  float4 a1 = *(const float4*)&Ahi[kb];
  float4 b0 = *(const float4*)&Blo[kb];
  float4 b1 = *(const float4*)&Bhi[kb];

  for (int k0 = kb; k0 < kb + Kc; k0 += 16) {
    __syncthreads();
    As[cS + 0][rS] = (double)a0.x; As[cS + 1][rS] = (double)a0.y;
    As[cS + 2][rS] = (double)a0.z; As[cS + 3][rS] = (double)a0.w;
    As[cS + 0][64 + rS] = (double)a1.x; As[cS + 1][64 + rS] = (double)a1.y;
    As[cS + 2][64 + rS] = (double)a1.z; As[cS + 3][64 + rS] = (double)a1.w;
    Bs[cS + 0][rS] = (double)b0.x; Bs[cS + 1][rS] = (double)b0.y;
    Bs[cS + 2][rS] = (double)b0.z; Bs[cS + 3][rS] = (double)b0.w;
    Bs[cS + 0][64 + rS] = (double)b1.x; Bs[cS + 1][64 + rS] = (double)b1.y;
    Bs[cS + 2][64 + rS] = (double)b1.z; Bs[cS + 3][64 + rS] = (double)b1.w;
    if (k0 + 16 < kb + Kc) {  // prefetch next k-step during compute
      a0 = *(const float4*)&Alo[k0 + 16];
      a1 = *(const float4*)&Ahi[k0 + 16];
      b0 = *(const float4*)&Blo[k0 + 16];
      b1 = *(const float4*)&Bhi[k0 + 16];
    }
    __syncthreads();
#pragma unroll
    for (int k = 0; k < 16; ++k) {
      double ar[8], br[8];
#pragma unroll
      for (int g = 0; g < 4; ++g) {
        const double2 av = *(const double2*)&As[k][32 * g + 2 * ty];
        ar[2 * g] = av.x; ar[2 * g + 1] = av.y;
        const double2 bv = *(const double2*)&Bs[k][32 * g + 2 * tx];
        br[2 * g] = bv.x; br[2 * g + 1] = bv.y;
      }
#pragma unroll
      for (int i = 0; i < 8; ++i)
#pragma unroll
        for (int j = 0; j < 8; ++j)
          acc[i][j] = fma(ar[i], br[j], acc[i][j]);
    }
  }

  double* Pp = P + (size_t)s * M * N;
#pragma unroll
  for (int i = 0; i < 8; ++i) {
    const int row = m0 + 32 * (i >> 1) + 2 * ty + (i & 1);
#pragma unroll
    for (int h = 0; h < 4; ++h) {
      const int col = n0 + 32 * h + 2 * tx;
      *(double2*)&Pp[(size_t)row * N + col] =
          make_double2(acc[i][2 * h], acc[i][2 * h + 1]);
    }
  }
}

// ---------------------------------------------------------------------------
// Reduce S f64 partials (ascending) + tanh epilogue on the f32 grid.
// ---------------------------------------------------------------------------
__global__ __launch_bounds__(256) void reduce_tanh(
    const double* __restrict__ P, int S, const float* __restrict__ bias,
    float* __restrict__ C, int N, int total) {
  const int idx = blockIdx.x * 256 + threadIdx.x;
  if (idx >= total) return;
  double sum = 0.0;
  for (int s = 0; s < S; ++s) sum += P[(size_t)s * total + idx];
  const float zg = (float)sum;
  const float z = zg + bias[idx % N];
  C[idx] = (float)tanh((double)z);
}

// ---------------------------------------------------------------------------
// Reduce partials + adjacency epilogue on the f32 grid.
// ---------------------------------------------------------------------------
__global__ __launch_bounds__(256) void reduce_adj(
    const double* __restrict__ P, int S, float* __restrict__ adj, int N) {
  const int idx = blockIdx.x * 256 + threadIdx.x;
  const int total = N * N;
  if (idx >= total) return;
  double sum = 0.0;
  for (int s = 0; s < S; ++s) sum += P[(size_t)s * total + idx];
  const float g = (float)sum;
  const float fid = g * g;
  float v = (fid >= 0.8f) ? 1.0f : ((fid >= 0.6f) ? 0.5f : 0.0f);
  if (idx / N == idx % N) v = 0.0f;
  adj[idx] = v;
}

// ---------------------------------------------------------------------------
__global__ __launch_bounds__(256) void rownorm(
    const float* __restrict__ last, float* __restrict__ nrm) {
  const int b = blockIdx.x;
  const int t = threadIdx.x;
  const float v = last[(size_t)b * 256 + t];
  const float sq = v * v;
  double s = (double)sq;
#pragma unroll
  for (int o = 32; o > 0; o >>= 1) s += __shfl_down(s, o);
  __shared__ double red[4];
  if ((t & 63) == 0) red[t >> 6] = s;
  __syncthreads();
  const double total = red[0] + red[1] + red[2] + red[3];
  const float s32 = (float)total;
  const float den = sqrtf(s32) + 1e-12f;
  nrm[(size_t)b * 256 + t] = v / den;
}

// ---------------------------------------------------------------------------
__global__ __launch_bounds__(256) void bn_stats(
    const float* __restrict__ last, const float* __restrict__ gamma,
    const float* __restrict__ beta, float* __restrict__ out) {
  const int j = blockIdx.x;
  const int t = threadIdx.x;
  double v[4];
  double s = 0.0;
#pragma unroll
  for (int i = 0; i < 4; ++i) {
    v[i] = (double)last[(size_t)(i * 256 + t) * 256 + j];
    s += v[i];
  }
#pragma unroll
  for (int o = 32; o > 0; o >>= 1) s += __shfl_down(s, o);
  __shared__ double red[4];
  if ((t & 63) == 0) red[t >> 6] = s;
  __syncthreads();
  const double mean = (red[0] + red[1] + red[2] + red[3]) * (1.0 / 1024.0);
  double q = 0.0;
#pragma unroll
  for (int i = 0; i < 4; ++i) {
    const double d = v[i] - mean;
    q += d * d;
  }
#pragma unroll
  for (int o = 32; o > 0; o >>= 1) q += __shfl_down(q, o);
  __syncthreads();
  if ((t & 63) == 0) red[t >> 6] = q;
  __syncthreads();
  const double var = (red[0] + red[1] + red[2] + red[3]) * (1.0 / 1024.0);
  const double g = (double)gamma[j] / sqrt(var + 1e-5);
  const double be = (double)beta[j];
#pragma unroll
  for (int i = 0; i < 4; ++i)
    out[(size_t)(i * 256 + t) * 256 + j] = (float)((v[i] - mean) * g + be);
}

// ---------------------------------------------------------------------------
extern "C" void kernel_launch(void* const* d_in, const int* in_sizes, int n_in,
                              void* d_out, int out_size, void* d_ws,
                              size_t ws_size, hipStream_t stream) {
  const float* x     = (const float*)d_in[0];
  const float* cw1   = (const float*)d_in[1];
  const float* cb1   = (const float*)d_in[2];
  const float* cw2   = (const float*)d_in[3];
  const float* cb2   = (const float*)d_in[4];
  const float* w1    = (const float*)d_in[5];   // [1024,4096]
  const float* b1    = (const float*)d_in[6];
  const float* w2    = (const float*)d_in[7];   // [256,1024]
  const float* b2    = (const float*)d_in[8];
  const float* gamma = (const float*)d_in[9];
  const float* beta  = (const float*)d_in[10];

  float* outp = (float*)d_out;            // [1024,256]
  float* adj  = outp + 1024 * 256;        // [1024,1024]

  float* ws   = (float*)d_ws;
  float* flat = ws;                       // [1024,4096] @0        16.78 MB
  float* h1   = ws + 4194304;             // [1024,1024]            4.19 MB
  float* last = ws + 5242880;             // [1024,256]             1.05 MB
  float* nrm  = ws + 5505024;             // [1024,256]             1.05 MB
  double* part = (double*)(ws + 5767168); // partial region @23.07 MB
  float* feat1 = (float*)part;            // [1024,8,32,32] 33.55 MB,
                                          // dead before first GEMM

  // ws gates (deterministic): S1=8 partials 67.1MB -> 90.2MB total;
  // S1=4 -> 56.6MB; else S1=2 + fused conv (feat1 wouldn't fit).
  const size_t baseB = 5767168ull * 4ull;
  int S1;
  if (ws_size >= baseB + 8ull * 1024 * 1024 * 8) S1 = 8;
  else if (ws_size >= baseB + 4ull * 1024 * 1024 * 8) S1 = 4;
  else S1 = 2;
  const int S2 = (S1 >= 4) ? 16 : 4;      // gemm2 partials: 33.5MB / 8.4MB
  const int S3 = (S1 == 8) ? 4 : 2;       // gram partials: 33.5MB / 16.8MB
  const bool split_conv = (S1 >= 4);

  if (split_conv) {
    conv1_kernel<<<1024, 256, 0, stream>>>(x, cw1, cb1, feat1);
    conv2_kernel<<<1024, 256, 0, stream>>>(feat1, cw2, cb2, flat);
  } else {
    conv_fused<<<1024, 256, 0, stream>>>(x, cw1, cb1, cw2, cb2, flat);
  }

  // h1 = tanh(flat @ w1^T + b1)   [1024,1024], K=4096
  gemm_nt_f64_v3<<<dim3(8, 8, S1), 256, 0, stream>>>(
      flat, w1, part, 1024, 1024, 4096, 4096 / S1);
  reduce_tanh<<<4096, 256, 0, stream>>>(part, S1, b1, h1, 1024, 1024 * 1024);

  // last = tanh(h1 @ w2^T + b2)   [1024,256], K=1024
  gemm_nt_f64_v3<<<dim3(2, 8, S2), 256, 0, stream>>>(
      h1, w2, part, 1024, 256, 1024, 1024 / S2);
  reduce_tanh<<<1024, 256, 0, stream>>>(part, S2, b2, last, 256, 1024 * 256);

  rownorm<<<1024, 256, 0, stream>>>(last, nrm);

  // adj = thr((nrm @ nrm^T)^2), zero diag; K=256
  gemm_nt_f64_v3<<<dim3(8, 8, S3), 256, 0, stream>>>(
      nrm, nrm, part, 1024, 1024, 256, 256 / S3);
  reduce_adj<<<4096, 256, 0, stream>>>(part, S3, adj, 1024);

  bn_stats<<<256, 256, 0, stream>>>(last, gamma, beta, outp);
}

// Round 7
// 426.682 us; speedup vs baseline: 1.2476x; 1.0049x over previous
//
#include <hip/hip_runtime.h>
#include <hip/hip_bf16.h>
#include <math.h>

// ===========================================================================
// f64-accumulate / f32-storage-grid pipeline (R2/R3 numerics, proven).
// R6: GEMM1 split-K 16 (4 blocks/CU; R5's 128x128 tile ran at 2 blocks/CU,
// occupancy 17.7%); rownorm fused into GEMM2's reduce (bit-identical
// reduction order); gram adjacency computed directly (no partials).
// ===========================================================================

// ---------------------------------------------------------------------------
// conv1: conv(1->8,3x3,SAME) + bias + relu + maxpool2 -> feat1 [1024,8,32,32]
// ---------------------------------------------------------------------------
__global__ __launch_bounds__(256) void conv1_kernel(
    const float* __restrict__ x, const float* __restrict__ cw1,
    const float* __restrict__ cb1, float* __restrict__ feat1) {
  __shared__ float sX[66 * 66];
  __shared__ float sW1[72];
  __shared__ float sB1[8];

  const int b = blockIdx.x;
  const int t = threadIdx.x;

  for (int i = t; i < 66 * 66; i += 256) sX[i] = 0.0f;
  if (t < 72) sW1[t] = cw1[t];
  if (t < 8)  sB1[t] = cb1[t];
  __syncthreads();

  const float* xb = x + (size_t)b * 4096;
  for (int i = t; i < 4096; i += 256)
    sX[((i >> 6) + 1) * 66 + (i & 63) + 1] = xb[i];
  __syncthreads();

  for (int task = t; task < 2048; task += 256) {
    const int ch = task >> 8;
    const int rem = task & 255;
    const int py = rem >> 3;
    const int px0 = (rem & 7) * 4;

    double w9[9];
#pragma unroll
    for (int k = 0; k < 9; ++k) w9[k] = (double)sW1[ch * 9 + k];

    float reg[4][10];
#pragma unroll
    for (int r = 0; r < 4; ++r)
#pragma unroll
      for (int c = 0; c < 5; ++c) {
        const float2 v =
            *(const float2*)&sX[(2 * py + r) * 66 + 2 * px0 + 2 * c];
        reg[r][2 * c] = v.x;
        reg[r][2 * c + 1] = v.y;
      }

    float out4[4];
#pragma unroll
    for (int px = 0; px < 4; ++px) {
      double best = -1e300;
#pragma unroll
      for (int dy = 0; dy < 2; ++dy) {
#pragma unroll
        for (int dx = 0; dx < 2; ++dx) {
          double s = 0.0;
#pragma unroll
          for (int ky = 0; ky < 3; ++ky)
#pragma unroll
            for (int kx = 0; kx < 3; ++kx)
              s = fma((double)reg[dy + ky][2 * px + dx + kx], w9[ky * 3 + kx],
                      s);
          best = fmax(best, s);
        }
      }
      out4[px] = (float)fmax(best + (double)sB1[ch], 0.0);
    }
    *(float4*)&feat1[(size_t)b * 8192 + ch * 1024 + py * 32 + px0] =
        make_float4(out4[0], out4[1], out4[2], out4[3]);
  }
}

// ---------------------------------------------------------------------------
// conv2 (R5-proven, no spill): conv(8->16)+bias+relu+pool -> flat [1024,4096]
// ---------------------------------------------------------------------------
__global__ __launch_bounds__(256) void conv2_kernel(
    const float* __restrict__ feat1, const float* __restrict__ cw2,
    const float* __restrict__ cb2, float* __restrict__ flat) {
  __shared__ float sF[8 * 34 * 34];
  __shared__ float sW2[1152];
  __shared__ float sB2[16];

  const int b = blockIdx.x;
  const int t = threadIdx.x;

  for (int i = t; i < 8 * 34 * 34; i += 256) sF[i] = 0.0f;
  for (int i = t; i < 1152; i += 256) sW2[i] = cw2[i];
  if (t < 16) sB2[t] = cb2[t];
  __syncthreads();

  const float* fb = feat1 + (size_t)b * 8192;
  for (int i = t; i < 8192; i += 256) {
    const int ch = i >> 10, pos = i & 1023;
    sF[ch * 1156 + ((pos >> 5) + 1) * 34 + (pos & 31) + 1] = fb[i];
  }
  __syncthreads();

  const int py = t >> 4, px = t & 15;
  float* ob = flat + (size_t)b * 4096 + py * 16 + px;

#pragma unroll 1
  for (int oh = 0; oh < 2; ++oh) {
    double acc[8][4];
#pragma unroll
    for (int o = 0; o < 8; ++o)
#pragma unroll
      for (int q = 0; q < 4; ++q) acc[o][q] = 0.0;

#pragma unroll
    for (int ic = 0; ic < 8; ++ic) {
      float r[4][4];
#pragma unroll
      for (int iy = 0; iy < 4; ++iy) {
        const float2 v0 =
            *(const float2*)&sF[ic * 1156 + (2 * py + iy) * 34 + 2 * px];
        const float2 v1 =
            *(const float2*)&sF[ic * 1156 + (2 * py + iy) * 34 + 2 * px + 2];
        r[iy][0] = v0.x; r[iy][1] = v0.y; r[iy][2] = v1.x; r[iy][3] = v1.y;
      }
#pragma unroll
      for (int o = 0; o < 8; ++o) {
        const float* w = &sW2[(oh * 8 + o) * 72 + ic * 9];
        double w9[9];
#pragma unroll
        for (int k = 0; k < 9; ++k) w9[k] = (double)w[k];
#pragma unroll
        for (int dy = 0; dy < 2; ++dy)
#pragma unroll
          for (int dx = 0; dx < 2; ++dx) {
            double s = acc[o][dy * 2 + dx];
#pragma unroll
            for (int ky = 0; ky < 3; ++ky)
#pragma unroll
              for (int kx = 0; kx < 3; ++kx)
                s = fma((double)r[dy + ky][dx + kx], w9[ky * 3 + kx], s);
            acc[o][dy * 2 + dx] = s;
          }
      }
    }
#pragma unroll
    for (int o = 0; o < 8; ++o) {
      const int oc = oh * 8 + o;
      const double best =
          fmax(fmax(acc[o][0], acc[o][1]), fmax(acc[o][2], acc[o][3]));
      ob[oc * 256] = (float)fmax(best + (double)sB2[oc], 0.0);
    }
  }
}

// ---------------------------------------------------------------------------
// Fallback fused conv (R2/R3 kernel) for small-ws path.
// ---------------------------------------------------------------------------
__global__ __launch_bounds__(256) void conv_fused(
    const float* __restrict__ x,
    const float* __restrict__ cw1, const float* __restrict__ cb1,
    const float* __restrict__ cw2, const float* __restrict__ cb2,
    float* __restrict__ flat) {
  __shared__ float sX[66 * 66];
  __shared__ float sF[8 * 34 * 34];
  __shared__ float sW1[72];
  __shared__ float sW2[1152];
  __shared__ float sB1[8];
  __shared__ float sB2[16];

  const int b = blockIdx.x;
  const int t = threadIdx.x;

  for (int i = t; i < 66 * 66; i += 256) sX[i] = 0.0f;
  for (int i = t; i < 8 * 34 * 34; i += 256) sF[i] = 0.0f;
  if (t < 72) sW1[t] = cw1[t];
  for (int i = t; i < 1152; i += 256) sW2[i] = cw2[i];
  if (t < 8)  sB1[t] = cb1[t];
  if (t < 16) sB2[t] = cb2[t];
  __syncthreads();

  const float* xb = x + (size_t)b * 4096;
  for (int i = t; i < 4096; i += 256)
    sX[((i >> 6) + 1) * 66 + (i & 63) + 1] = xb[i];
  __syncthreads();

  for (int p = t; p < 8192; p += 256) {
    const int ch = p >> 10, pos = p & 1023;
    const int py1 = pos >> 5, px1 = pos & 31;
    double best = -1e300;
#pragma unroll
    for (int dy = 0; dy < 2; ++dy)
#pragma unroll
      for (int dx = 0; dx < 2; ++dx) {
        const int y = 2 * py1 + dy, xx = 2 * px1 + dx;
        double s = 0.0;
#pragma unroll
        for (int ky = 0; ky < 3; ++ky)
#pragma unroll
          for (int kx = 0; kx < 3; ++kx)
            s = fma((double)sX[(y + ky) * 66 + xx + kx],
                    (double)sW1[ch * 9 + ky * 3 + kx], s);
        best = fmax(best, s);
      }
    sF[ch * 1156 + (py1 + 1) * 34 + px1 + 1] =
        (float)fmax(best + (double)sB1[ch], 0.0);
  }
  __syncthreads();

  const int py = t >> 4, px = t & 15;
  for (int oh = 0; oh < 2; ++oh) {
    double acc[8][4];
#pragma unroll
    for (int o = 0; o < 8; ++o)
#pragma unroll
      for (int q = 0; q < 4; ++q) acc[o][q] = 0.0;
#pragma unroll
    for (int ic = 0; ic < 8; ++ic) {
      double r[4][4];
#pragma unroll
      for (int iy = 0; iy < 4; ++iy)
#pragma unroll
        for (int ix = 0; ix < 4; ++ix)
          r[iy][ix] = (double)sF[ic * 1156 + (2 * py + iy) * 34 + 2 * px + ix];
#pragma unroll
      for (int o = 0; o < 8; ++o) {
        const float* w = &sW2[(oh * 8 + o) * 72 + ic * 9];
        double w9[9];
#pragma unroll
        for (int k = 0; k < 9; ++k) w9[k] = (double)w[k];
#pragma unroll
        for (int dy = 0; dy < 2; ++dy)
#pragma unroll
          for (int dx = 0; dx < 2; ++dx) {
            double s = acc[o][dy * 2 + dx];
#pragma unroll
            for (int ky = 0; ky < 3; ++ky)
#pragma unroll
              for (int kx = 0; kx < 3; ++kx)
                s = fma(r[dy + ky][dx + kx], w9[ky * 3 + kx], s);
            acc[o][dy * 2 + dx] = s;
          }
      }
    }
    float* ob = flat + (size_t)b * 4096 + py * 16 + px;
#pragma unroll
    for (int o = 0; o < 8; ++o) {
      const int oc = oh * 8 + o;
      double best =
          fmax(fmax(acc[o][0], acc[o][1]), fmax(acc[o][2], acc[o][3]));
      ob[oc * 256] = (float)fmax(best + (double)sB2[oc], 0.0);
    }
  }
}

// ---------------------------------------------------------------------------
// Split-K NT GEMM v3 (R5-proven): 128x128 tile, BK=16, 8x8 microtile,
// f64 accumulate, software-pipelined global prefetch, k ascending per chunk.
// ---------------------------------------------------------------------------
__global__ __launch_bounds__(256) void gemm_nt_f64_v3(
    const float* __restrict__ A, const float* __restrict__ B,
    double* __restrict__ P, int M, int N, int K, int Kc) {
  __shared__ double As[16][130];
  __shared__ double Bs[16][130];

  const int t = threadIdx.x;
  const int n0 = blockIdx.x * 128;
  const int m0 = blockIdx.y * 128;
  const int s  = blockIdx.z;
  const int kb = s * Kc;
  const int rS = t >> 2;
  const int cS = (t & 3) * 4;
  const int ty = t >> 4;
  const int tx = t & 15;

  double acc[8][8];
#pragma unroll
  for (int i = 0; i < 8; ++i)
#pragma unroll
    for (int j = 0; j < 8; ++j) acc[i][j] = 0.0;

  const float* Alo = &A[(size_t)(m0 + rS) * K + cS];
  const float* Ahi = &A[(size_t)(m0 + 64 + rS) * K + cS];
  const float* Blo = &B[(size_t)(n0 + rS) * K + cS];
  const float* Bhi = &B[(size_t)(n0 + 64 + rS) * K + cS];

  float4 a0 = *(const float4*)&Alo[kb];
  float4 a1 = *(const float4*)&Ahi[kb];
  float4 b0 = *(const float4*)&Blo[kb];
  float4 b1 = *(const float4*)&Bhi[kb];

  for (int k0 = kb; k0 < kb + Kc; k0 += 16) {
    __syncthreads();
    As[cS + 0][rS] = (double)a0.x; As[cS + 1][rS] = (double)a0.y;
    As[cS + 2][rS] = (double)a0.z; As[cS + 3][rS] = (double)a0.w;
    As[cS + 0][64 + rS] = (double)a1.x; As[cS + 1][64 + rS] = (double)a1.y;
    As[cS + 2][64 + rS] = (double)a1.z; As[cS + 3][64 + rS] = (double)a1.w;
    Bs[cS + 0][rS] = (double)b0.x; Bs[cS + 1][rS] = (double)b0.y;
    Bs[cS + 2][rS] = (double)b0.z; Bs[cS + 3][rS] = (double)b0.w;
    Bs[cS + 0][64 + rS] = (double)b1.x; Bs[cS + 1][64 + rS] = (double)b1.y;
    Bs[cS + 2][64 + rS] = (double)b1.z; Bs[cS + 3][64 + rS] = (double)b1.w;
    if (k0 + 16 < kb + Kc) {
      a0 = *(const float4*)&Alo[k0 + 16];
      a1 = *(const float4*)&Ahi[k0 + 16];
      b0 = *(const float4*)&Blo[k0 + 16];
      b1 = *(const float4*)&Bhi[k0 + 16];
    }
    __syncthreads();
#pragma unroll
    for (int k = 0; k < 16; ++k) {
      double ar[8], br[8];
#pragma unroll
      for (int g = 0; g < 4; ++g) {
        const double2 av = *(const double2*)&As[k][32 * g + 2 * ty];
        ar[2 * g] = av.x; ar[2 * g + 1] = av.y;
        const double2 bv = *(const double2*)&Bs[k][32 * g + 2 * tx];
        br[2 * g] = bv.x; br[2 * g + 1] = bv.y;
      }
#pragma unroll
      for (int i = 0; i < 8; ++i)
#pragma unroll
        for (int j = 0; j < 8; ++j)
          acc[i][j] = fma(ar[i], br[j], acc[i][j]);
    }
  }

  double* Pp = P + (size_t)s * M * N;
#pragma unroll
  for (int i = 0; i < 8; ++i) {
    const int row = m0 + 32 * (i >> 1) + 2 * ty + (i & 1);
#pragma unroll
    for (int h = 0; h < 4; ++h) {
      const int col = n0 + 32 * h + 2 * tx;
      *(double2*)&Pp[(size_t)row * N + col] =
          make_double2(acc[i][2 * h], acc[i][2 * h + 1]);
    }
  }
}

// ---------------------------------------------------------------------------
// Reduce S f64 partials (ascending) + tanh epilogue on the f32 grid.
// ---------------------------------------------------------------------------
__global__ __launch_bounds__(256) void reduce_tanh(
    const double* __restrict__ P, int S, const float* __restrict__ bias,
    float* __restrict__ C, int N, int total) {
  const int idx = blockIdx.x * 256 + threadIdx.x;
  if (idx >= total) return;
  double sum = 0.0;
  for (int s = 0; s < S; ++s) sum += P[(size_t)s * total + idx];
  const float zg = (float)sum;
  const float z = zg + bias[idx % N];
  C[idx] = (float)tanh((double)z);
}

// ---------------------------------------------------------------------------
// GEMM2 reduce + tanh + row-L2-normalize, fused. One block per row (N=256
// cols = 256 threads). Reduction order bit-identical to the proven rownorm.
// ---------------------------------------------------------------------------
__global__ __launch_bounds__(256) void reduce_tanh_norm(
    const double* __restrict__ P, int S, const float* __restrict__ bias,
    float* __restrict__ last, float* __restrict__ nrm) {
  const int b = blockIdx.x;
  const int t = threadIdx.x;
  const int idx = b * 256 + t;
  const int total = 1024 * 256;
  double sum = 0.0;
  for (int s = 0; s < S; ++s) sum += P[(size_t)s * total + idx];
  const float zg = (float)sum;
  const float z = zg + bias[t];
  const float v = (float)tanh((double)z);
  last[idx] = v;

  const float sq = v * v;
  double s = (double)sq;
#pragma unroll
  for (int o = 32; o > 0; o >>= 1) s += __shfl_down(s, o);
  __shared__ double red[4];
  if ((t & 63) == 0) red[t >> 6] = s;
  __syncthreads();
  const double totalSq = red[0] + red[1] + red[2] + red[3];
  const float s32 = (float)totalSq;
  const float den = sqrtf(s32) + 1e-12f;
  nrm[idx] = v / den;
}

// ---------------------------------------------------------------------------
// Gram + threshold adjacency, direct (no partials): 64x64 tile, BK=16,
// 4x4 microtile with 2+2 split columns, f64 accumulate k ascending, K=256.
// g = f32(acc); fid = g*g; 0.8f/0.6f cutoffs; diag zeroed.
// ---------------------------------------------------------------------------
__global__ __launch_bounds__(256) void gram_adj_direct(
    const float* __restrict__ Nrm, float* __restrict__ adj, int Msz, int K) {
  __shared__ double As[16][66];
  __shared__ double Bs[16][66];

  const int t = threadIdx.x;
  const int n0 = blockIdx.x * 64;
  const int m0 = blockIdx.y * 64;
  const int lm = t >> 2;
  const int lk4 = (t & 3) * 4;
  const int ty = t >> 4;
  const int tx = t & 15;

  double acc[4][4];
#pragma unroll
  for (int i = 0; i < 4; ++i)
#pragma unroll
    for (int j = 0; j < 4; ++j) acc[i][j] = 0.0;

  for (int k0 = 0; k0 < K; k0 += 16) {
    const float4 av = *(const float4*)&Nrm[(size_t)(m0 + lm) * K + k0 + lk4];
    const float4 bv = *(const float4*)&Nrm[(size_t)(n0 + lm) * K + k0 + lk4];
    __syncthreads();
    As[lk4 + 0][lm] = (double)av.x; As[lk4 + 1][lm] = (double)av.y;
    As[lk4 + 2][lm] = (double)av.z; As[lk4 + 3][lm] = (double)av.w;
    Bs[lk4 + 0][lm] = (double)bv.x; Bs[lk4 + 1][lm] = (double)bv.y;
    Bs[lk4 + 2][lm] = (double)bv.z; Bs[lk4 + 3][lm] = (double)bv.w;
    __syncthreads();
#pragma unroll
    for (int k = 0; k < 16; ++k) {
      const double2 a01 = *(const double2*)&As[k][2 * ty];
      const double2 a23 = *(const double2*)&As[k][32 + 2 * ty];
      const double2 b01 = *(const double2*)&Bs[k][2 * tx];
      const double2 b23 = *(const double2*)&Bs[k][32 + 2 * tx];
      const double ar[4] = {a01.x, a01.y, a23.x, a23.y};
      const double br[4] = {b01.x, b01.y, b23.x, b23.y};
#pragma unroll
      for (int i = 0; i < 4; ++i)
#pragma unroll
        for (int j = 0; j < 4; ++j)
          acc[i][j] = fma(ar[i], br[j], acc[i][j]);
    }
  }

  const int rows[4] = {m0 + 2 * ty, m0 + 2 * ty + 1,
                       m0 + 32 + 2 * ty, m0 + 32 + 2 * ty + 1};
  const int cols[4] = {n0 + 2 * tx, n0 + 2 * tx + 1,
                       n0 + 32 + 2 * tx, n0 + 32 + 2 * tx + 1};
#pragma unroll
  for (int i = 0; i < 4; ++i)
#pragma unroll
    for (int j = 0; j < 4; ++j) {
      const float g = (float)acc[i][j];
      const float fid = g * g;
      float v = (fid >= 0.8f) ? 1.0f : ((fid >= 0.6f) ? 0.5f : 0.0f);
      if (rows[i] == cols[j]) v = 0.0f;
      adj[(size_t)rows[i] * Msz + cols[j]] = v;
    }
}

// ---------------------------------------------------------------------------
// BatchNorm1d training mode (unchanged, proven).
// ---------------------------------------------------------------------------
__global__ __launch_bounds__(256) void bn_stats(
    const float* __restrict__ last, const float* __restrict__ gamma,
    const float* __restrict__ beta, float* __restrict__ out) {
  const int j = blockIdx.x;
  const int t = threadIdx.x;
  double v[4];
  double s = 0.0;
#pragma unroll
  for (int i = 0; i < 4; ++i) {
    v[i] = (double)last[(size_t)(i * 256 + t) * 256 + j];
    s += v[i];
  }
#pragma unroll
  for (int o = 32; o > 0; o >>= 1) s += __shfl_down(s, o);
  __shared__ double red[4];
  if ((t & 63) == 0) red[t >> 6] = s;
  __syncthreads();
  const double mean = (red[0] + red[1] + red[2] + red[3]) * (1.0 / 1024.0);
  double q = 0.0;
#pragma unroll
  for (int i = 0; i < 4; ++i) {
    const double d = v[i] - mean;
    q += d * d;
  }
#pragma unroll
  for (int o = 32; o > 0; o >>= 1) q += __shfl_down(q, o);
  __syncthreads();
  if ((t & 63) == 0) red[t >> 6] = q;
  __syncthreads();
  const double var = (red[0] + red[1] + red[2] + red[3]) * (1.0 / 1024.0);
  const double g = (double)gamma[j] / sqrt(var + 1e-5);
  const double be = (double)beta[j];
#pragma unroll
  for (int i = 0; i < 4; ++i)
    out[(size_t)(i * 256 + t) * 256 + j] = (float)((v[i] - mean) * g + be);
}

// ---------------------------------------------------------------------------
extern "C" void kernel_launch(void* const* d_in, const int* in_sizes, int n_in,
                              void* d_out, int out_size, void* d_ws,
                              size_t ws_size, hipStream_t stream) {
  const float* x     = (const float*)d_in[0];
  const float* cw1   = (const float*)d_in[1];
  const float* cb1   = (const float*)d_in[2];
  const float* cw2   = (const float*)d_in[3];
  const float* cb2   = (const float*)d_in[4];
  const float* w1    = (const float*)d_in[5];   // [1024,4096]
  const float* b1    = (const float*)d_in[6];
  const float* w2    = (const float*)d_in[7];   // [256,1024]
  const float* b2    = (const float*)d_in[8];
  const float* gamma = (const float*)d_in[9];
  const float* beta  = (const float*)d_in[10];

  float* outp = (float*)d_out;            // [1024,256]
  float* adj  = outp + 1024 * 256;        // [1024,1024]

  float* ws   = (float*)d_ws;
  float* flat = ws;                       // [1024,4096] @0        16.78 MB
  float* h1   = ws + 4194304;             // [1024,1024]            4.19 MB
  float* last = ws + 5242880;             // [1024,256]             1.05 MB
  float* nrm  = ws + 5505024;             // [1024,256]             1.05 MB
  double* part = (double*)(ws + 5767168); // partial region @23.07 MB
  float* feat1 = (float*)part;            // [1024,8,32,32] 33.55 MB,
                                          // dead before first GEMM

  // ws gates (deterministic): S1=16 -> 157.3MB total; 8 -> 90.2MB;
  // 4 -> 56.6MB; else 2 + fused conv (feat1 wouldn't fit).
  const size_t baseB = 5767168ull * 4ull;
  int S1;
  if (ws_size >= baseB + 16ull * 1024 * 1024 * 8) S1 = 16;
  else if (ws_size >= baseB + 8ull * 1024 * 1024 * 8) S1 = 8;
  else if (ws_size >= baseB + 4ull * 1024 * 1024 * 8) S1 = 4;
  else S1 = 2;
  const int S2 = (S1 >= 4) ? 16 : 4;      // gemm2 partials: 33.5MB / 8.4MB
  const bool split_conv = (S1 >= 4);

  if (split_conv) {
    conv1_kernel<<<1024, 256, 0, stream>>>(x, cw1, cb1, feat1);
    conv2_kernel<<<1024, 256, 0, stream>>>(feat1, cw2, cb2, flat);
  } else {
    conv_fused<<<1024, 256, 0, stream>>>(x, cw1, cb1, cw2, cb2, flat);
  }

  // h1 = tanh(flat @ w1^T + b1)   [1024,1024], K=4096
  gemm_nt_f64_v3<<<dim3(8, 8, S1), 256, 0, stream>>>(
      flat, w1, part, 1024, 1024, 4096, 4096 / S1);
  reduce_tanh<<<4096, 256, 0, stream>>>(part, S1, b1, h1, 1024, 1024 * 1024);

  // last = tanh(h1 @ w2^T + b2), then rownorm, fused reduce
  gemm_nt_f64_v3<<<dim3(2, 8, S2), 256, 0, stream>>>(
      h1, w2, part, 1024, 256, 1024, 1024 / S2);
  reduce_tanh_norm<<<1024, 256, 0, stream>>>(part, S2, b2, last, nrm);

  // adj = thr((nrm @ nrm^T)^2), zero diag; K=256, direct (no partials)
  gram_adj_direct<<<dim3(16, 16), 256, 0, stream>>>(nrm, adj, 1024, 256);

  bn_stats<<<256, 256, 0, stream>>>(last, gamma, beta, outp);
}